// Round 1
// baseline (899.105 us; speedup 1.0000x reference)
//
#include <hip/hip_runtime.h>
#include <cstdint>

// Problem constants (from reference)
constexpr int G = 4, N = 50000, E = 800000;
constexpr int FIN = 64, HID = 128, FOUT = 64;
constexpr int NB = (N + 1023) / 1024;  // scan blocks per graph = 49

// ---------------- utility kernels ----------------
__global__ void k_zero_int(int* p, int n) {
  int i = blockIdx.x * blockDim.x + threadIdx.x;
  if (i < n) p[i] = 0;
}

// count in-degree (dst occurrences) per node
__global__ void k_deg(const int* __restrict__ ei, int* __restrict__ cnt) {
  int i = blockIdx.x * blockDim.x + threadIdx.x;  // over G*E
  if (i >= G * E) return;
  int g = i / E, e = i - g * E;
  int dst = ei[(size_t)g * 2 * E + E + e];
  atomicAdd(&cnt[g * N + dst], 1);
}

// ---- 3-kernel exclusive scan of cnt -> rowptr (per graph) ----
__global__ void k_scan_partial(const int* __restrict__ cnt, int* __restrict__ part) {
  int g = blockIdx.y, b = blockIdx.x, tid = threadIdx.x;
  int base = b * 1024 + tid * 4;
  int s = 0;
#pragma unroll
  for (int k = 0; k < 4; ++k) {
    int i = base + k;
    if (i < N) s += cnt[g * N + i];
  }
  __shared__ int sm[256];
  sm[tid] = s;
  __syncthreads();
  for (int off = 128; off > 0; off >>= 1) {
    if (tid < off) sm[tid] += sm[tid + off];
    __syncthreads();
  }
  if (tid == 0) part[g * NB + b] = sm[0];
}

__global__ void k_scan_mid(int* __restrict__ part, int* __restrict__ rowptr) {
  int g = blockIdx.x;
  if (threadIdx.x != 0) return;
  int run = 0;
  for (int b = 0; b < NB; ++b) {
    int t = part[g * NB + b];
    part[g * NB + b] = run;
    run += t;
  }
  rowptr[g * (N + 1) + N] = run;  // == E
}

__global__ void k_scan_final(const int* __restrict__ cnt, const int* __restrict__ part,
                             int* __restrict__ rowptr) {
  int g = blockIdx.y, b = blockIdx.x, tid = threadIdx.x;
  int base = b * 1024 + tid * 4;
  int c[4];
  int s = 0;
#pragma unroll
  for (int k = 0; k < 4; ++k) {
    int i = base + k;
    c[k] = (i < N) ? cnt[g * N + i] : 0;
    s += c[k];
  }
  __shared__ int sm[256];
  sm[tid] = s;
  __syncthreads();
  for (int off = 1; off < 256; off <<= 1) {
    int v = (tid >= off) ? sm[tid - off] : 0;
    __syncthreads();
    sm[tid] += v;
    __syncthreads();
  }
  int excl = sm[tid] - s + part[g * NB + b];
#pragma unroll
  for (int k = 0; k < 4; ++k) {
    int i = base + k;
    if (i < N) rowptr[g * (N + 1) + i] = excl;
    excl += c[k];
  }
}

// dinv = rsqrt(indeg + 1 self loop); reset cnt for use as fill cursor
__global__ void k_dinv(int* __restrict__ cnt, float* __restrict__ dinv) {
  int i = blockIdx.x * blockDim.x + threadIdx.x;
  if (i >= G * N) return;
  dinv[i] = rsqrtf((float)(cnt[i] + 1));
  cnt[i] = 0;
}

__global__ void k_fill(const int* __restrict__ ei, const int* __restrict__ rowptr,
                       int* __restrict__ cur, int* __restrict__ col) {
  int i = blockIdx.x * blockDim.x + threadIdx.x;
  if (i >= G * E) return;
  int g = i / E, e = i - g * E;
  int src = ei[(size_t)g * 2 * E + e];
  int dst = ei[(size_t)g * 2 * E + E + e];
  int pos = atomicAdd(&cur[g * N + dst], 1);
  col[(size_t)g * E + rowptr[g * (N + 1) + dst] + pos] = src;
}

// ---------------- GEMM: Hout[g,i,:] = dinv[g,i] * (X[g,i,:] @ W[g]) ----------------
// W staged in LDS (32 KB); each thread computes 4 adjacent output cols of one row.
template <int K, int F>
__global__ __launch_bounds__(256) void k_gemm(const float* __restrict__ X,
                                              const float* __restrict__ W,
                                              const float* __restrict__ dinv,
                                              float* __restrict__ Hout) {
  constexpr int CPR = F / 4;      // threads per row (32 or 16)
  constexpr int RPI = 256 / CPR;  // rows per iteration (8 or 16)
  __shared__ __align__(16) float ws[K * F];
  __shared__ __align__(16) float xs[RPI * K];
  int g = blockIdx.y;
  const float* Wg = W + (size_t)g * K * F;
  for (int idx = threadIdx.x; idx < K * F; idx += 256) ws[idx] = Wg[idx];
  int R0 = blockIdx.x * 64;
  int rr = threadIdx.x / CPR;
  int c4 = (threadIdx.x % CPR) * 4;
  for (int r0 = 0; r0 < 64; r0 += RPI) {
    __syncthreads();  // xs readers from previous iter done (and covers ws on first pass)
    for (int idx = threadIdx.x; idx < RPI * K; idx += 256) {
      int row = R0 + r0 + idx / K;
      xs[idx] = (row < N) ? X[((size_t)g * N + row) * K + (idx % K)] : 0.f;
    }
    __syncthreads();
    int row = R0 + r0 + rr;
    float4 acc = {0.f, 0.f, 0.f, 0.f};
    const float* xrow = &xs[rr * K];
#pragma unroll
    for (int k = 0; k < K; ++k) {
      float xv = xrow[k];
      const float4 w4 = *(const float4*)&ws[k * F + c4];
      acc.x += xv * w4.x;
      acc.y += xv * w4.y;
      acc.z += xv * w4.z;
      acc.w += xv * w4.w;
    }
    if (row < N) {
      float sc = dinv[g * N + row];
      float4 o = {acc.x * sc, acc.y * sc, acc.z * sc, acc.w * sc};
      *(float4*)&Hout[((size_t)g * N + row) * F + c4] = o;
    }
  }
}

// ---------------- aggregation: one wave per dst node ----------------
// out[d,:] = ELU(dinv[d] * (Hsrc[d,:] + sum_{s in in(d)} Hsrc[s,:]) + bias)
template <int F>
__global__ __launch_bounds__(256) void k_agg(const float* __restrict__ Hsrc,
                                             const int* __restrict__ rowptr,
                                             const int* __restrict__ col,
                                             const float* __restrict__ dinv,
                                             const float* __restrict__ bias,
                                             float* __restrict__ out) {
  int w = blockIdx.x * 4 + (threadIdx.x >> 6);  // grid = G*N/4 exactly
  int lane = threadIdx.x & 63;
  int g = w / N, d = w - g * N;
  const float* hb = Hsrc + (size_t)g * N * F;
  const int* cl = col + (size_t)g * E;
  int rs = rowptr[g * (N + 1) + d];
  int re = rowptr[g * (N + 1) + d + 1];
  float a0, a1 = 0.f;
  if (F == 128) {
    float2 v = *(const float2*)&hb[(size_t)d * F + lane * 2];
    a0 = v.x;
    a1 = v.y;
  } else {
    a0 = hb[(size_t)d * F + lane];
  }
  for (int j0 = rs; j0 < re; j0 += 64) {
    int myc = (j0 + lane < re) ? cl[j0 + lane] : 0;  // lane-parallel index prefetch
    int nn = min(64, re - j0);
    int jj = 0;
    for (; jj + 4 <= nn; jj += 4) {
      int s0 = __shfl(myc, jj, 64);
      int s1 = __shfl(myc, jj + 1, 64);
      int s2 = __shfl(myc, jj + 2, 64);
      int s3 = __shfl(myc, jj + 3, 64);
      if (F == 128) {
        float2 v0 = *(const float2*)&hb[(size_t)s0 * F + lane * 2];
        float2 v1 = *(const float2*)&hb[(size_t)s1 * F + lane * 2];
        float2 v2 = *(const float2*)&hb[(size_t)s2 * F + lane * 2];
        float2 v3 = *(const float2*)&hb[(size_t)s3 * F + lane * 2];
        a0 += v0.x + v1.x + v2.x + v3.x;
        a1 += v0.y + v1.y + v2.y + v3.y;
      } else {
        float v0 = hb[(size_t)s0 * F + lane];
        float v1 = hb[(size_t)s1 * F + lane];
        float v2 = hb[(size_t)s2 * F + lane];
        float v3 = hb[(size_t)s3 * F + lane];
        a0 += v0 + v1 + v2 + v3;
      }
    }
    for (; jj < nn; ++jj) {
      int s = __shfl(myc, jj, 64);
      if (F == 128) {
        float2 v = *(const float2*)&hb[(size_t)s * F + lane * 2];
        a0 += v.x;
        a1 += v.y;
      } else {
        a0 += hb[(size_t)s * F + lane];
      }
    }
  }
  float sc = dinv[g * N + d];
  if (F == 128) {
    float p0 = a0 * sc + bias[g * F + lane * 2];
    float p1 = a1 * sc + bias[g * F + lane * 2 + 1];
    p0 = p0 > 0.f ? p0 : expm1f(p0);
    p1 = p1 > 0.f ? p1 : expm1f(p1);
    float2 o = {p0, p1};
    *(float2*)&out[((size_t)g * N + d) * F + lane * 2] = o;
  } else {
    float p0 = a0 * sc + bias[g * F + lane];
    p0 = p0 > 0.f ? p0 : expm1f(p0);
    out[((size_t)g * N + d) * F + lane] = p0;
  }
}

extern "C" void kernel_launch(void* const* d_in, const int* in_sizes, int n_in,
                              void* d_out, int out_size, void* d_ws, size_t ws_size,
                              hipStream_t stream) {
  const float* x = (const float*)d_in[0];
  const int* ei = (const int*)d_in[1];
  const float* W1 = (const float*)d_in[2];
  const float* b1 = (const float*)d_in[3];
  const float* W2 = (const float*)d_in[4];
  const float* b2 = (const float*)d_in[5];
  float* out = (float*)d_out;

  // Workspace carve-up (~219 MB needed; 256B aligned chunks)
  char* p = (char*)d_ws;
  auto alloc = [&](size_t bytes) {
    char* r = p;
    p += (bytes + 255) & ~(size_t)255;
    return r;
  };
  int* cnt = (int*)alloc(sizeof(int) * G * N);
  int* rowptr = (int*)alloc(sizeof(int) * G * (N + 1));
  int* part = (int*)alloc(sizeof(int) * G * NB);
  float* dinv = (float*)alloc(sizeof(float) * G * N);
  int* col = (int*)alloc(sizeof(int) * (size_t)G * E);
  float* h1s = (float*)alloc(sizeof(float) * (size_t)G * N * HID);
  float* h1 = (float*)alloc(sizeof(float) * (size_t)G * N * HID);

  // 1. in-degree
  k_zero_int<<<(G * N + 255) / 256, 256, 0, stream>>>(cnt, G * N);
  k_deg<<<(G * E + 255) / 256, 256, 0, stream>>>(ei, cnt);
  // 2. rowptr = exclusive scan of degrees (per graph)
  dim3 sg(NB, G);
  k_scan_partial<<<sg, 256, 0, stream>>>(cnt, part);
  k_scan_mid<<<G, 64, 0, stream>>>(part, rowptr);
  k_scan_final<<<sg, 256, 0, stream>>>(cnt, part, rowptr);
  // 3. dinv (deg+1 self loop), reset cursor
  k_dinv<<<(G * N + 255) / 256, 256, 0, stream>>>(cnt, dinv);
  // 4. fill CSR col (src list per dst)
  k_fill<<<(G * E + 255) / 256, 256, 0, stream>>>(ei, rowptr, cnt, col);
  // 5. layer 1: h1s = dinv*(x@W1); h1 = ELU(dinv*(agg h1s) + b1)
  dim3 gg((N + 63) / 64, G);
  k_gemm<FIN, HID><<<gg, 256, 0, stream>>>(x, W1, dinv, h1s);
  k_agg<HID><<<(G * N) / 4, 256, 0, stream>>>(h1s, rowptr, col, dinv, b1, h1);
  // 6. layer 2: h2s reuses h1s buffer; final ELU straight to d_out
  float* h2s = h1s;
  k_gemm<HID, FOUT><<<gg, 256, 0, stream>>>(h1, W2, dinv, h2s);
  k_agg<FOUT><<<(G * N) / 4, 256, 0, stream>>>(h2s, rowptr, col, dinv, b2, out);
}